// Round 2
// baseline (472.860 us; speedup 1.0000x reference)
//
#include <hip/hip_runtime.h>
#include <hip/hip_bf16.h>

#define NN 50000
#define NE 800000
#define HF 128

// workspace byte offsets (256-aligned), total 43,868,672 B (~41.8 MB)
#define OFF_FLAG   0u
#define OFF_ROWPTR 256u         // 50001 * 4
#define OFF_DEG    200704u      // 50000 * 4
#define OFF_FILL   400896u      // 50000 * 4
#define OFF_ADJ    601088u      // 800000 * 4
#define OFF_FX     3801088u     // 6,400,000 bf16 (canonical feats)
#define OFF_WC1    16601088u    // 16384 bf16
#define OFF_WC2    16633856u    // 16384 bf16
#define OFF_PAR    16666624u    // 8 slots * 256 B: al1,ar1,b1,al2,ar2,b2,Wp,bp
#define OFF_Z      16668672u    // 6,400,000 bf16
#define OFF_H1     29468672u    // 6,400,000 bf16
#define OFF_EL     42268672u    // 200000 f32
#define OFF_ER     43068672u    // 200000 f32

typedef __hip_bfloat16 bf16;
typedef unsigned short us16;

__device__ __forceinline__ float us2f(us16 u) {
  union { unsigned int i; float f; } c; c.i = ((unsigned int)u) << 16; return c.f;
}
__device__ __forceinline__ us16 f2us(float f) {
  bf16 h = __float2bfloat16(f);
  union { bf16 h; us16 u; } c; c.h = h; return c.u;
}

// ---- dtype detection: bf16 inputs have exponent field <= ~126 (|w|<1);
// f32 inputs read as ushort have uniform low-halves -> exp >= 135 certain.
__global__ __launch_bounds__(64) void k_detect(const void* __restrict__ w1raw,
                                               int* __restrict__ flag) {
  const us16* u = (const us16*)w1raw;
  int lane = threadIdx.x;
  int mx = 0;
  for (int i = lane; i < 2048; i += 64) {
    int e = (u[i] >> 7) & 0xFF;
    mx = mx > e ? mx : e;
  }
#pragma unroll
  for (int m = 32; m >= 1; m >>= 1) {
    int o = __shfl_xor(mx, m);
    mx = mx > o ? mx : o;
  }
  if (lane == 0) *flag = (mx >= 135) ? 1 : 0;  // 1 = inputs are f32
}

__global__ __launch_bounds__(256) void k_canon_feats(const void* __restrict__ src,
                                                     us16* __restrict__ dst,
                                                     const int* __restrict__ flag) {
  int i = (blockIdx.x * 256 + threadIdx.x) * 4;
  if (i >= NN * HF) return;
  if (*flag) {
    float4 v = *(const float4*)((const float*)src + i);
    ushort4 o;
    o.x = f2us(v.x); o.y = f2us(v.y); o.z = f2us(v.z); o.w = f2us(v.w);
    *(ushort4*)(dst + i) = o;
  } else {
    *(ushort4*)(dst + i) = *(const ushort4*)((const us16*)src + i);
  }
}

__global__ __launch_bounds__(256) void k_canon_small(
    const void* s0, const void* s1, const void* s2, const void* s3, const void* s4,
    const void* s5, const void* s6, const void* s7, const void* s8, const void* s9,
    us16* d0, us16* d1, us16* d2, us16* d3, us16* d4,
    us16* d5, us16* d6, us16* d7, us16* d8, us16* d9,
    const int* __restrict__ flag) {
  const void* sp[10] = {s0, s1, s2, s3, s4, s5, s6, s7, s8, s9};
  us16* dp[10] = {d0, d1, d2, d3, d4, d5, d6, d7, d8, d9};
  const int cnt[10] = {16384, 16384, 128, 128, 128, 128, 128, 128, 32, 1};
  int f = *flag;
  for (int p = 0; p < 10; ++p)
    for (int i = threadIdx.x; i < cnt[p]; i += 256)
      dp[p][i] = f ? f2us(((const float*)sp[p])[i]) : ((const us16*)sp[p])[i];
}

// ---- CSR build
__global__ void k_count(const int* __restrict__ dst, int* __restrict__ deg) {
  int e = blockIdx.x * 256 + threadIdx.x;
  if (e < NE) atomicAdd(&deg[dst[e]], 1);
}

__global__ __launch_bounds__(1024) void k_scan(const int* __restrict__ deg,
                                               int* __restrict__ rowptr) {
  __shared__ int part[1024];
  int t = threadIdx.x;
  const int CH = (NN + 1023) / 1024;  // 49
  int lo = t * CH, hi = lo + CH;
  if (hi > NN) hi = NN;
  if (lo > NN) lo = NN;
  int s = 0;
  for (int i = lo; i < hi; ++i) s += deg[i];
  part[t] = s;
  __syncthreads();
  for (int off = 1; off < 1024; off <<= 1) {
    int v = (t >= off) ? part[t - off] : 0;
    __syncthreads();
    part[t] += v;
    __syncthreads();
  }
  int run = part[t] - s;  // exclusive prefix
  for (int i = lo; i < hi; ++i) { rowptr[i] = run; run += deg[i]; }
  if (t == 1023) rowptr[NN] = part[1023];
}

__global__ void k_scatter(const int* __restrict__ src, const int* __restrict__ dst,
                          const int* __restrict__ rowptr, int* __restrict__ fill,
                          int* __restrict__ adj) {
  int e = blockIdx.x * 256 + threadIdx.x;
  if (e < NE) {
    int d = dst[e];
    int pos = rowptr[d] + atomicAdd(&fill[d], 1);
    adj[pos] = src[e];
  }
}

// ---- Z[N,128](bf16) = X[N,128](bf16) @ W[128,128](bf16), f32 accumulate
__global__ __launch_bounds__(256) void k_gemm(const us16* __restrict__ X,
                                              const us16* __restrict__ W,
                                              us16* __restrict__ Z) {
  __shared__ us16 Wl[HF * HF];
  int t = threadIdx.x;
  for (int i = t * 4; i < HF * HF; i += 1024)
    *(ushort4*)&Wl[i] = *(const ushort4*)&W[i];
  __syncthreads();
  int tx = t & 31, ty = t >> 5;
  int row0 = blockIdx.x * 32 + ty * 4;
  float acc[4][4] = {};
  const us16* xp[4];
  int rows[4];
#pragma unroll
  for (int r = 0; r < 4; ++r) {
    int rr = row0 + r;
    rows[r] = rr;
    xp[r] = X + (size_t)(rr < NN ? rr : NN - 1) * HF;
  }
#pragma unroll 4
  for (int k = 0; k < HF; ++k) {
    ushort4 wu = *(ushort4*)&Wl[k * HF + tx * 4];
    float w0 = us2f(wu.x), w1 = us2f(wu.y), w2 = us2f(wu.z), w3 = us2f(wu.w);
#pragma unroll
    for (int r = 0; r < 4; ++r) {
      float xv = us2f(xp[r][k]);
      acc[r][0] = fmaf(xv, w0, acc[r][0]);
      acc[r][1] = fmaf(xv, w1, acc[r][1]);
      acc[r][2] = fmaf(xv, w2, acc[r][2]);
      acc[r][3] = fmaf(xv, w3, acc[r][3]);
    }
  }
#pragma unroll
  for (int r = 0; r < 4; ++r) {
    if (rows[r] < NN) {
      ushort4 o;
      o.x = f2us(acc[r][0]); o.y = f2us(acc[r][1]);
      o.z = f2us(acc[r][2]); o.w = f2us(acc[r][3]);
      *(ushort4*)&Z[(size_t)rows[r] * HF + tx * 4] = o;
    }
  }
}

// el[n,h] = sum_f z[n,h,f]*al[h,f]; er likewise. 2 nodes per 256-thr block.
__global__ __launch_bounds__(256) void k_coef(const us16* __restrict__ Z,
                                              const us16* __restrict__ al,
                                              const us16* __restrict__ ar,
                                              float* __restrict__ el,
                                              float* __restrict__ er) {
  int t = threadIdx.x;
  int n = blockIdx.x * 2 + (t >> 7);
  int c = t & 127;
  float v = us2f(Z[(size_t)n * HF + c]);
  float pl = v * us2f(al[c]);
  float pr = v * us2f(ar[c]);
#pragma unroll
  for (int m = 16; m >= 1; m >>= 1) {
    pl += __shfl_xor(pl, m);
    pr += __shfl_xor(pr, m);
  }
  if ((c & 31) == 0) {
    int h = c >> 5;
    el[n * 4 + h] = pl;
    er[n * 4 + h] = pr;
  }
}

// One wave per destination node: softmax over in-edges + weighted aggregation.
template <int LAYER>
__global__ __launch_bounds__(64) void k_agg(
    const us16* __restrict__ Z, const float* __restrict__ el,
    const float* __restrict__ er, const int* __restrict__ rowptr,
    const int* __restrict__ adj, const us16* __restrict__ resid,
    const us16* __restrict__ bias, us16* __restrict__ Hout,
    const us16* __restrict__ Wp, const us16* __restrict__ bp,
    void* __restrict__ out, const int* __restrict__ flag) {
  __shared__ float scb[64 * 4];
  __shared__ int sidx[64];
  int n = blockIdx.x;
  int lane = threadIdx.x;
  int begin = rowptr[n];
  int deg = rowptr[n + 1] - begin;
  float4 er4 = *(const float4*)&er[n * 4];
  int hl = lane >> 4;   // head owning this lane's feature pair
  int c0 = lane * 2;    // feature pair c0, c0+1
  float m4[4] = {-1e30f, -1e30f, -1e30f, -1e30f};
  // pass 1: per-head max of leaky_relu(el[src]+er[n])
  for (int i = lane; i < deg; i += 64) {
    int s = adj[begin + i];
    s = ((unsigned)s < (unsigned)NN) ? s : 0;  // defensive clamp
    float4 e4 = *(const float4*)&el[s * 4];
    float s0 = e4.x + er4.x; s0 = s0 > 0.f ? s0 : 0.2f * s0;
    float s1 = e4.y + er4.y; s1 = s1 > 0.f ? s1 : 0.2f * s1;
    float s2 = e4.z + er4.z; s2 = s2 > 0.f ? s2 : 0.2f * s2;
    float s3 = e4.w + er4.w; s3 = s3 > 0.f ? s3 : 0.2f * s3;
    m4[0] = fmaxf(m4[0], s0); m4[1] = fmaxf(m4[1], s1);
    m4[2] = fmaxf(m4[2], s2); m4[3] = fmaxf(m4[3], s3);
  }
#pragma unroll
  for (int mm = 32; mm >= 1; mm >>= 1) {
#pragma unroll
    for (int h = 0; h < 4; ++h) m4[h] = fmaxf(m4[h], __shfl_xor(m4[h], mm));
  }
  float mh = m4[hl];
  // pass 2: ssum = sum exp, a = sum exp * z[src]
  float a0 = 0.f, a1 = 0.f, ssum = 0.f;
  for (int base = 0; base < deg; base += 64) {
    int cl = deg - base;
    if (cl > 64) cl = 64;
    __syncthreads();  // protect LDS reuse across chunks
    if (lane < cl) {
      int s = adj[begin + base + lane];
      s = ((unsigned)s < (unsigned)NN) ? s : 0;
      float4 e4 = *(const float4*)&el[s * 4];
      float s0 = e4.x + er4.x; s0 = s0 > 0.f ? s0 : 0.2f * s0;
      float s1 = e4.y + er4.y; s1 = s1 > 0.f ? s1 : 0.2f * s1;
      float s2 = e4.z + er4.z; s2 = s2 > 0.f ? s2 : 0.2f * s2;
      float s3 = e4.w + er4.w; s3 = s3 > 0.f ? s3 : 0.2f * s3;
      scb[lane * 4 + 0] = s0; scb[lane * 4 + 1] = s1;
      scb[lane * 4 + 2] = s2; scb[lane * 4 + 3] = s3;
      sidx[lane] = s;
    }
    __syncthreads();
    for (int i = 0; i < cl; ++i) {
      int s = sidx[i];
      float ex = __expf(scb[i * 4 + hl] - mh);
      ssum += ex;
      unsigned int zz = *(const unsigned int*)&Z[(size_t)s * HF + c0];
      float z0 = us2f((us16)(zz & 0xffffu));
      float z1 = us2f((us16)(zz >> 16));
      a0 = fmaf(ex, z0, a0);
      a1 = fmaf(ex, z1, a1);
    }
  }
  float inv = 1.f / fmaxf(ssum, 1e-9f);  // deg==0 -> a==0 -> r==0 (matches ref)
  float r0 = a0 * inv, r1 = a1 * inv;
  float bb0 = us2f(bias[c0]), bb1 = us2f(bias[c0 + 1]);
  float x0 = us2f(resid[(size_t)n * HF + c0]);
  float x1 = us2f(resid[(size_t)n * HF + c0 + 1]);
  float t0 = r0 + x0 + bb0;
  float t1 = r1 + x1 + bb1;
  if (LAYER == 1) {
    t0 = t0 > 0.f ? t0 : __expf(t0) - 1.f;  // ELU
    t1 = t1 > 0.f ? t1 : __expf(t1) - 1.f;
    unsigned int hv = ((unsigned int)f2us(t1) << 16) | (unsigned int)f2us(t0);
    *(unsigned int*)&Hout[(size_t)n * HF + c0] = hv;
  } else {
    // mean over heads: lanes {l, l^16, l^32, l^48} share the same feature pair
    t0 += __shfl_xor(t0, 16); t0 += __shfl_xor(t0, 32);
    t1 += __shfl_xor(t1, 16); t1 += __shfl_xor(t1, 32);
    t0 *= 0.25f; t1 *= 0.25f;
    // projection: each 16-lane group covers f=0..31 via its 2-feature pairs
    int f0 = c0 & 31;
    float p = t0 * us2f(Wp[f0]) + t1 * us2f(Wp[f0 + 1]);
    p += __shfl_xor(p, 8); p += __shfl_xor(p, 4);
    p += __shfl_xor(p, 2); p += __shfl_xor(p, 1);
    if (lane == 0) {
      float res = p + us2f(bp[0]);
      if (*flag) ((float*)out)[n] = res;
      else ((us16*)out)[n] = f2us(res);
    }
  }
}

extern "C" void kernel_launch(void* const* d_in, const int* in_sizes, int n_in,
                              void* d_out, int out_size, void* d_ws, size_t ws_size,
                              hipStream_t stream) {
  const int* src = (const int*)d_in[1];
  const int* dst = (const int*)d_in[2];
  char* ws = (char*)d_ws;
  int* flag   = (int*)(ws + OFF_FLAG);
  int* rowptr = (int*)(ws + OFF_ROWPTR);
  int* deg    = (int*)(ws + OFF_DEG);
  int* fill   = (int*)(ws + OFF_FILL);
  int* adj    = (int*)(ws + OFF_ADJ);
  us16* fx    = (us16*)(ws + OFF_FX);
  us16* wc1   = (us16*)(ws + OFF_WC1);
  us16* wc2   = (us16*)(ws + OFF_WC2);
  us16* al1   = (us16*)(ws + OFF_PAR + 0);
  us16* ar1   = (us16*)(ws + OFF_PAR + 256);
  us16* b1    = (us16*)(ws + OFF_PAR + 512);
  us16* al2   = (us16*)(ws + OFF_PAR + 768);
  us16* ar2   = (us16*)(ws + OFF_PAR + 1024);
  us16* b2    = (us16*)(ws + OFF_PAR + 1280);
  us16* wp    = (us16*)(ws + OFF_PAR + 1536);
  us16* bp    = (us16*)(ws + OFF_PAR + 1792);
  us16* z     = (us16*)(ws + OFF_Z);
  us16* h1    = (us16*)(ws + OFF_H1);
  float* el   = (float*)(ws + OFF_EL);
  float* er   = (float*)(ws + OFF_ER);

  hipMemsetAsync(deg, 0, OFF_ADJ - OFF_DEG, stream);  // zero deg + fill

  hipLaunchKernelGGL(k_detect, dim3(1), dim3(64), 0, stream, d_in[3], flag);
  hipLaunchKernelGGL(k_canon_feats, dim3(6250), dim3(256), 0, stream, d_in[0], fx, flag);
  hipLaunchKernelGGL(k_canon_small, dim3(1), dim3(256), 0, stream,
                     d_in[3], d_in[7], d_in[4], d_in[5], d_in[6],
                     d_in[8], d_in[9], d_in[10], d_in[11], d_in[12],
                     wc1, wc2, al1, ar1, b1, al2, ar2, b2, wp, bp, flag);

  hipLaunchKernelGGL(k_count, dim3(3125), dim3(256), 0, stream, dst, deg);
  hipLaunchKernelGGL(k_scan, dim3(1), dim3(1024), 0, stream, deg, rowptr);
  hipLaunchKernelGGL(k_scatter, dim3(3125), dim3(256), 0, stream, src, dst, rowptr, fill, adj);

  // layer 1
  hipLaunchKernelGGL(k_gemm, dim3((NN + 31) / 32), dim3(256), 0, stream, fx, wc1, z);
  hipLaunchKernelGGL(k_coef, dim3(NN / 2), dim3(256), 0, stream, z, al1, ar1, el, er);
  hipLaunchKernelGGL((k_agg<1>), dim3(NN), dim3(64), 0, stream, z, el, er, rowptr, adj,
                     fx, b1, h1, (us16*)nullptr, (us16*)nullptr, (void*)nullptr, flag);
  // layer 2 (+ fused head-mean and projection)
  hipLaunchKernelGGL(k_gemm, dim3((NN + 31) / 32), dim3(256), 0, stream, h1, wc2, z);
  hipLaunchKernelGGL(k_coef, dim3(NN / 2), dim3(256), 0, stream, z, al2, ar2, el, er);
  hipLaunchKernelGGL((k_agg<2>), dim3(NN), dim3(64), 0, stream, z, el, er, rowptr, adj,
                     h1, b2, (us16*)nullptr, wp, bp, d_out, flag);
}

// Round 4
// 372.008 us; speedup vs baseline: 1.2711x; 1.2711x over previous
//
#include <hip/hip_runtime.h>
#include <hip/hip_bf16.h>

#define NN 50000
#define NE 800000
#define HF 128

// workspace byte offsets (256-aligned), total 43,868,672 B (~41.8 MB, proven in R2)
#define OFF_FLAG   0u
#define OFF_ROWPTR 256u         // 50001 * 4 = 200004 used; region ends 200704
#define OFF_BSUM   200272u      // 49*4 bsum + pad -> fits in rowptr region slack
#define OFF_BOFF   200480u      // 49*4 boff; 200480+196=200676 <= 200704 OK
#define OFF_DEG    200704u      // 50000 * 4
#define OFF_FILL   400896u      // 50000 * 4
#define OFF_ADJ    601088u      // 800000 * 4
#define OFF_FX     3801088u     // 6,400,000 bf16 (canonical feats)
#define OFF_WC1    16601088u    // 16384 bf16
#define OFF_WC2    16633856u    // 16384 bf16
#define OFF_PAR    16666624u    // 8 slots * 256 B: al1,ar1,b1,al2,ar2,b2,Wp,bp
#define OFF_Z      16668672u    // 6,400,000 bf16
#define OFF_H1     29468672u    // 6,400,000 bf16
#define OFF_EL     42268672u    // 200000 f32
#define OFF_ER     43068672u    // 200000 f32

typedef __hip_bfloat16 bf16;
typedef unsigned short us16;

#define N_SMALL 33569  // 16384+16384+6*128+32+1 elements in k_canon_small

__device__ __forceinline__ float us2f(us16 u) {
  union { unsigned int i; float f; } c; c.i = ((unsigned int)u) << 16; return c.f;
}
__device__ __forceinline__ us16 f2us(float f) {
  bf16 h = __float2bfloat16(f);
  union { bf16 h; us16 u; } c; c.h = h; return c.u;
}

// ---- dtype detection: bf16 inputs have exponent field <= ~126 (|w|<1);
// f32 inputs read as ushort have uniform low-halves -> exp >= 135 certain.
__global__ __launch_bounds__(64) void k_detect(const void* __restrict__ w1raw,
                                               int* __restrict__ flag) {
  const us16* u = (const us16*)w1raw;
  int lane = threadIdx.x;
  int mx = 0;
  for (int i = lane; i < 2048; i += 64) {
    int e = (u[i] >> 7) & 0xFF;
    mx = mx > e ? mx : e;
  }
#pragma unroll
  for (int m = 32; m >= 1; m >>= 1) {
    int o = __shfl_xor(mx, m);
    mx = mx > o ? mx : o;
  }
  if (lane == 0) *flag = (mx >= 135) ? 1 : 0;  // 1 = inputs are f32
}

__global__ __launch_bounds__(256) void k_canon_feats(const void* __restrict__ src,
                                                     us16* __restrict__ dst,
                                                     const int* __restrict__ flag) {
  int i = (blockIdx.x * 256 + threadIdx.x) * 4;
  if (i >= NN * HF) return;
  if (*flag) {
    float4 v = *(const float4*)((const float*)src + i);
    ushort4 o;
    o.x = f2us(v.x); o.y = f2us(v.y); o.z = f2us(v.z); o.w = f2us(v.w);
    *(ushort4*)(dst + i) = o;
  } else {
    *(ushort4*)(dst + i) = *(const ushort4*)((const us16*)src + i);
  }
}

// parallel small-param canonicalization: grid covers all N_SMALL elems
__global__ __launch_bounds__(256) void k_canon_small(
    const void* s0, const void* s1, const void* s2, const void* s3, const void* s4,
    const void* s5, const void* s6, const void* s7, const void* s8, const void* s9,
    us16* d0, us16* d1, us16* d2, us16* d3, us16* d4,
    us16* d5, us16* d6, us16* d7, us16* d8, us16* d9,
    const int* __restrict__ flag) {
  const void* sp[10] = {s0, s1, s2, s3, s4, s5, s6, s7, s8, s9};
  us16* dp[10] = {d0, d1, d2, d3, d4, d5, d6, d7, d8, d9};
  const int cnt[10] = {16384, 16384, 128, 128, 128, 128, 128, 128, 32, 1};
  int f = *flag;
  int gid = blockIdx.x * 256 + threadIdx.x;
  int base = 0;
#pragma unroll
  for (int p = 0; p < 10; ++p) {
    int loc = gid - base;
    if (loc >= 0 && loc < cnt[p])
      dp[p][loc] = f ? f2us(((const float*)sp[p])[loc]) : ((const us16*)sp[p])[loc];
    base += cnt[p];
  }
}

// ---- CSR build
__global__ void k_count(const int* __restrict__ dst, int* __restrict__ deg) {
  int e = blockIdx.x * 256 + threadIdx.x;
  if (e < NE) atomicAdd(&deg[dst[e]], 1);
}

// hierarchical scan phase 1: per-block (1024 nodes) degree sums
__global__ __launch_bounds__(1024) void k_s1(const int* __restrict__ deg,
                                             int* __restrict__ bsum) {
  __shared__ int red[1024];
  int t = threadIdx.x;
  int i = blockIdx.x * 1024 + t;
  red[t] = (i < NN) ? deg[i] : 0;
  __syncthreads();
  for (int s = 512; s > 0; s >>= 1) {
    if (t < s) red[t] += red[t + s];
    __syncthreads();
  }
  if (t == 0) bsum[blockIdx.x] = red[0];
}

// phase 2: one wave scans the 49 block sums -> exclusive block offsets
__global__ __launch_bounds__(64) void k_s2(const int* __restrict__ bsum,
                                           int* __restrict__ boff,
                                           int* __restrict__ rowptr) {
  int lane = threadIdx.x;
  const int NB = (NN + 1023) / 1024;  // 49
  int v = (lane < NB) ? bsum[lane] : 0;
  int orig = v;
#pragma unroll
  for (int off = 1; off < 64; off <<= 1) {
    int u = __shfl_up(v, off);
    if (lane >= off) v += u;
  }
  if (lane < NB) boff[lane] = v - orig;  // exclusive
  if (lane == 0) rowptr[NN] = NE;
}

// phase 3: per-block Hillis-Steele exclusive scan + block offset -> rowptr
__global__ __launch_bounds__(1024) void k_s3(const int* __restrict__ deg,
                                             const int* __restrict__ boff,
                                             int* __restrict__ rowptr) {
  __shared__ int part[1024];
  int t = threadIdx.x;
  int i = blockIdx.x * 1024 + t;
  int d = (i < NN) ? deg[i] : 0;
  part[t] = d;
  __syncthreads();
  for (int off = 1; off < 1024; off <<= 1) {
    int v = (t >= off) ? part[t - off] : 0;
    __syncthreads();
    part[t] += v;
    __syncthreads();
  }
  if (i < NN) rowptr[i] = boff[blockIdx.x] + part[t] - d;
}

__global__ void k_scatter(const int* __restrict__ src, const int* __restrict__ dst,
                          const int* __restrict__ rowptr, int* __restrict__ fill,
                          int* __restrict__ adj) {
  int e = blockIdx.x * 256 + threadIdx.x;
  if (e < NE) {
    int d = dst[e];
    int pos = rowptr[d] + atomicAdd(&fill[d], 1);
    adj[pos] = src[e];
  }
}

// ---- Z[N,128](bf16) = X[N,128](bf16) @ W[128,128](bf16), f32 accumulate
__global__ __launch_bounds__(256) void k_gemm(const us16* __restrict__ X,
                                              const us16* __restrict__ W,
                                              us16* __restrict__ Z) {
  __shared__ us16 Wl[HF * HF];
  int t = threadIdx.x;
  for (int i = t * 4; i < HF * HF; i += 1024)
    *(ushort4*)&Wl[i] = *(const ushort4*)&W[i];
  __syncthreads();
  int tx = t & 31, ty = t >> 5;
  int row0 = blockIdx.x * 32 + ty * 4;
  float acc[4][4] = {};
  const us16* xp[4];
  int rows[4];
#pragma unroll
  for (int r = 0; r < 4; ++r) {
    int rr = row0 + r;
    rows[r] = rr;
    xp[r] = X + (size_t)(rr < NN ? rr : NN - 1) * HF;
  }
#pragma unroll 4
  for (int k = 0; k < HF; ++k) {
    ushort4 wu = *(ushort4*)&Wl[k * HF + tx * 4];
    float w0 = us2f(wu.x), w1 = us2f(wu.y), w2 = us2f(wu.z), w3 = us2f(wu.w);
#pragma unroll
    for (int r = 0; r < 4; ++r) {
      float xv = us2f(xp[r][k]);
      acc[r][0] = fmaf(xv, w0, acc[r][0]);
      acc[r][1] = fmaf(xv, w1, acc[r][1]);
      acc[r][2] = fmaf(xv, w2, acc[r][2]);
      acc[r][3] = fmaf(xv, w3, acc[r][3]);
    }
  }
#pragma unroll
  for (int r = 0; r < 4; ++r) {
    if (rows[r] < NN) {
      ushort4 o;
      o.x = f2us(acc[r][0]); o.y = f2us(acc[r][1]);
      o.z = f2us(acc[r][2]); o.w = f2us(acc[r][3]);
      *(ushort4*)&Z[(size_t)rows[r] * HF + tx * 4] = o;
    }
  }
}

// el[n,h] = sum_f z[n,h,f]*al[h,f]; er likewise. 2 nodes per 256-thr block.
__global__ __launch_bounds__(256) void k_coef(const us16* __restrict__ Z,
                                              const us16* __restrict__ al,
                                              const us16* __restrict__ ar,
                                              float* __restrict__ el,
                                              float* __restrict__ er) {
  int t = threadIdx.x;
  int n = blockIdx.x * 2 + (t >> 7);
  int c = t & 127;
  float v = us2f(Z[(size_t)n * HF + c]);
  float pl = v * us2f(al[c]);
  float pr = v * us2f(ar[c]);
#pragma unroll
  for (int m = 16; m >= 1; m >>= 1) {
    pl += __shfl_xor(pl, m);
    pr += __shfl_xor(pr, m);
  }
  if ((c & 31) == 0) {
    int h = c >> 5;
    el[n * 4 + h] = pl;
    er[n * 4 + h] = pr;
  }
}

// One wave per destination node: softmax over in-edges + weighted aggregation.
template <int LAYER>
__global__ __launch_bounds__(64) void k_agg(
    const us16* __restrict__ Z, const float* __restrict__ el,
    const float* __restrict__ er, const int* __restrict__ rowptr,
    const int* __restrict__ adj, const us16* __restrict__ resid,
    const us16* __restrict__ bias, us16* __restrict__ Hout,
    const us16* __restrict__ Wp, const us16* __restrict__ bp,
    void* __restrict__ out, const int* __restrict__ flag) {
  __shared__ float scb[64 * 4];
  __shared__ int sidx[64];
  int n = blockIdx.x;
  int lane = threadIdx.x;
  int begin = rowptr[n];
  int deg = rowptr[n + 1] - begin;
  float4 er4 = *(const float4*)&er[n * 4];
  int hl = lane >> 4;   // head owning this lane's feature pair
  int c0 = lane * 2;    // feature pair c0, c0+1
  float m4[4] = {-1e30f, -1e30f, -1e30f, -1e30f};
  // pass 1: per-head max of leaky_relu(el[src]+er[n])
  for (int i = lane; i < deg; i += 64) {
    int s = adj[begin + i];
    s = ((unsigned)s < (unsigned)NN) ? s : 0;  // defensive clamp
    float4 e4 = *(const float4*)&el[s * 4];
    float s0 = e4.x + er4.x; s0 = s0 > 0.f ? s0 : 0.2f * s0;
    float s1 = e4.y + er4.y; s1 = s1 > 0.f ? s1 : 0.2f * s1;
    float s2 = e4.z + er4.z; s2 = s2 > 0.f ? s2 : 0.2f * s2;
    float s3 = e4.w + er4.w; s3 = s3 > 0.f ? s3 : 0.2f * s3;
    m4[0] = fmaxf(m4[0], s0); m4[1] = fmaxf(m4[1], s1);
    m4[2] = fmaxf(m4[2], s2); m4[3] = fmaxf(m4[3], s3);
  }
#pragma unroll
  for (int mm = 32; mm >= 1; mm >>= 1) {
#pragma unroll
    for (int h = 0; h < 4; ++h) m4[h] = fmaxf(m4[h], __shfl_xor(m4[h], mm));
  }
  float mh = m4[hl];
  // pass 2: ssum = sum exp, a = sum exp * z[src]
  float a0 = 0.f, a1 = 0.f, ssum = 0.f;
  for (int base = 0; base < deg; base += 64) {
    int cl = deg - base;
    if (cl > 64) cl = 64;
    __syncthreads();  // protect LDS reuse across chunks
    if (lane < cl) {
      int s = adj[begin + base + lane];
      s = ((unsigned)s < (unsigned)NN) ? s : 0;
      float4 e4 = *(const float4*)&el[s * 4];
      float s0 = e4.x + er4.x; s0 = s0 > 0.f ? s0 : 0.2f * s0;
      float s1 = e4.y + er4.y; s1 = s1 > 0.f ? s1 : 0.2f * s1;
      float s2 = e4.z + er4.z; s2 = s2 > 0.f ? s2 : 0.2f * s2;
      float s3 = e4.w + er4.w; s3 = s3 > 0.f ? s3 : 0.2f * s3;
      scb[lane * 4 + 0] = s0; scb[lane * 4 + 1] = s1;
      scb[lane * 4 + 2] = s2; scb[lane * 4 + 3] = s3;
      sidx[lane] = s;
    }
    __syncthreads();
    for (int i = 0; i < cl; ++i) {
      int s = sidx[i];
      float ex = __expf(scb[i * 4 + hl] - mh);
      ssum += ex;
      unsigned int zz = *(const unsigned int*)&Z[(size_t)s * HF + c0];
      float z0 = us2f((us16)(zz & 0xffffu));
      float z1 = us2f((us16)(zz >> 16));
      a0 = fmaf(ex, z0, a0);
      a1 = fmaf(ex, z1, a1);
    }
  }
  float inv = 1.f / fmaxf(ssum, 1e-9f);  // deg==0 -> a==0 -> r==0 (matches ref)
  float r0 = a0 * inv, r1 = a1 * inv;
  float bb0 = us2f(bias[c0]), bb1 = us2f(bias[c0 + 1]);
  float x0 = us2f(resid[(size_t)n * HF + c0]);
  float x1 = us2f(resid[(size_t)n * HF + c0 + 1]);
  float t0 = r0 + x0 + bb0;
  float t1 = r1 + x1 + bb1;
  if (LAYER == 1) {
    t0 = t0 > 0.f ? t0 : __expf(t0) - 1.f;  // ELU
    t1 = t1 > 0.f ? t1 : __expf(t1) - 1.f;
    unsigned int hv = ((unsigned int)f2us(t1) << 16) | (unsigned int)f2us(t0);
    *(unsigned int*)&Hout[(size_t)n * HF + c0] = hv;
  } else {
    // mean over heads: lanes {l, l^16, l^32, l^48} share the same feature pair
    t0 += __shfl_xor(t0, 16); t0 += __shfl_xor(t0, 32);
    t1 += __shfl_xor(t1, 16); t1 += __shfl_xor(t1, 32);
    t0 *= 0.25f; t1 *= 0.25f;
    // projection: each 16-lane group covers f=0..31 via its 2-feature pairs
    int f0 = c0 & 31;
    float p = t0 * us2f(Wp[f0]) + t1 * us2f(Wp[f0 + 1]);
    p += __shfl_xor(p, 8); p += __shfl_xor(p, 4);
    p += __shfl_xor(p, 2); p += __shfl_xor(p, 1);
    if (lane == 0) {
      float res = p + us2f(bp[0]);
      if (*flag) ((float*)out)[n] = res;
      else ((us16*)out)[n] = f2us(res);
    }
  }
}

extern "C" void kernel_launch(void* const* d_in, const int* in_sizes, int n_in,
                              void* d_out, int out_size, void* d_ws, size_t ws_size,
                              hipStream_t stream) {
  const int* src = (const int*)d_in[1];
  const int* dst = (const int*)d_in[2];
  char* ws = (char*)d_ws;
  int* flag   = (int*)(ws + OFF_FLAG);
  int* rowptr = (int*)(ws + OFF_ROWPTR);
  int* bsum   = (int*)(ws + OFF_BSUM);
  int* boff   = (int*)(ws + OFF_BOFF);
  int* deg    = (int*)(ws + OFF_DEG);
  int* fill   = (int*)(ws + OFF_FILL);
  int* adj    = (int*)(ws + OFF_ADJ);
  us16* fx    = (us16*)(ws + OFF_FX);
  us16* wc1   = (us16*)(ws + OFF_WC1);
  us16* wc2   = (us16*)(ws + OFF_WC2);
  us16* al1   = (us16*)(ws + OFF_PAR + 0);
  us16* ar1   = (us16*)(ws + OFF_PAR + 256);
  us16* b1    = (us16*)(ws + OFF_PAR + 512);
  us16* al2   = (us16*)(ws + OFF_PAR + 768);
  us16* ar2   = (us16*)(ws + OFF_PAR + 1024);
  us16* b2    = (us16*)(ws + OFF_PAR + 1280);
  us16* wp    = (us16*)(ws + OFF_PAR + 1536);
  us16* bp    = (us16*)(ws + OFF_PAR + 1792);
  us16* z     = (us16*)(ws + OFF_Z);
  us16* h1    = (us16*)(ws + OFF_H1);
  float* el   = (float*)(ws + OFF_EL);
  float* er   = (float*)(ws + OFF_ER);

  const int NB = (NN + 1023) / 1024;  // 49

  hipMemsetAsync(deg, 0, OFF_ADJ - OFF_DEG, stream);  // zero deg + fill

  hipLaunchKernelGGL(k_detect, dim3(1), dim3(64), 0, stream, d_in[3], flag);
  hipLaunchKernelGGL(k_canon_feats, dim3(6250), dim3(256), 0, stream, d_in[0], fx, flag);
  hipLaunchKernelGGL(k_canon_small, dim3((N_SMALL + 255) / 256), dim3(256), 0, stream,
                     d_in[3], d_in[7], d_in[4], d_in[5], d_in[6],
                     d_in[8], d_in[9], d_in[10], d_in[11], d_in[12],
                     wc1, wc2, al1, ar1, b1, al2, ar2, b2, wp, bp, flag);

  hipLaunchKernelGGL(k_count, dim3(3125), dim3(256), 0, stream, dst, deg);
  hipLaunchKernelGGL(k_s1, dim3(NB), dim3(1024), 0, stream, deg, bsum);
  hipLaunchKernelGGL(k_s2, dim3(1), dim3(64), 0, stream, bsum, boff, rowptr);
  hipLaunchKernelGGL(k_s3, dim3(NB), dim3(1024), 0, stream, deg, boff, rowptr);
  hipLaunchKernelGGL(k_scatter, dim3(3125), dim3(256), 0, stream, src, dst, rowptr, fill, adj);

  // layer 1
  hipLaunchKernelGGL(k_gemm, dim3((NN + 31) / 32), dim3(256), 0, stream, fx, wc1, z);
  hipLaunchKernelGGL(k_coef, dim3(NN / 2), dim3(256), 0, stream, z, al1, ar1, el, er);
  hipLaunchKernelGGL((k_agg<1>), dim3(NN), dim3(64), 0, stream, z, el, er, rowptr, adj,
                     fx, b1, h1, (us16*)nullptr, (us16*)nullptr, (void*)nullptr, flag);
  // layer 2 (+ fused head-mean and projection)
  hipLaunchKernelGGL(k_gemm, dim3((NN + 31) / 32), dim3(256), 0, stream, h1, wc2, z);
  hipLaunchKernelGGL(k_coef, dim3(NN / 2), dim3(256), 0, stream, z, al2, ar2, el, er);
  hipLaunchKernelGGL((k_agg<2>), dim3(NN), dim3(64), 0, stream, z, el, er, rowptr, adj,
                     h1, b2, (us16*)nullptr, wp, bp, d_out, flag);
}

// Round 5
// 323.119 us; speedup vs baseline: 1.4634x; 1.1513x over previous
//
#include <hip/hip_runtime.h>
#include <hip/hip_bf16.h>

#define NN 50000
#define NE 800000
#define HF 128

// workspace byte offsets (256-aligned), total 43,868,672 B (~41.8 MB, proven in R2)
#define OFF_FLAG   0u
#define OFF_ROWPTR 256u         // 50001 * 4 = 200004 used; region ends 200704
#define OFF_BSUM   200272u      // 49*4 bsum + pad -> fits in rowptr region slack
#define OFF_BOFF   200480u      // 49*4 boff; 200480+196=200676 <= 200704 OK
#define OFF_DEG    200704u      // 50000 * 4
#define OFF_FILL   400896u      // 50000 * 4
#define OFF_ADJ    601088u      // 800000 * 4
#define OFF_FX     3801088u     // 6,400,000 bf16 (canonical feats)
#define OFF_WC1    16601088u    // 16384 bf16
#define OFF_WC2    16633856u    // 16384 bf16
#define OFF_PAR    16666624u    // 8 slots * 256 B: al1,ar1,b1,al2,ar2,b2,Wp,bp
#define OFF_Z      16668672u    // 6,400,000 bf16
#define OFF_H1     29468672u    // 6,400,000 bf16
#define OFF_EL     42268672u    // 200000 f32
#define OFF_ER     43068672u    // 200000 f32

typedef __hip_bfloat16 bf16;
typedef unsigned short us16;

#define N_SMALL 33569  // 16384+16384+6*128+32+1 elements in k_canon_small

typedef __attribute__((ext_vector_type(8))) short bf16x8;   // MFMA A/B frag (4 VGPRs)
typedef __attribute__((ext_vector_type(4))) float f32x4;    // MFMA C/D frag

__device__ __forceinline__ float us2f(us16 u) {
  union { unsigned int i; float f; } c; c.i = ((unsigned int)u) << 16; return c.f;
}
__device__ __forceinline__ us16 f2us(float f) {
  bf16 h = __float2bfloat16(f);
  union { bf16 h; us16 u; } c; c.h = h; return c.u;
}

// ---- dtype detection: bf16 inputs have exponent field <= ~126 (|w|<1);
// f32 inputs read as ushort have uniform low-halves -> exp >= 135 certain.
__global__ __launch_bounds__(64) void k_detect(const void* __restrict__ w1raw,
                                               int* __restrict__ flag) {
  const us16* u = (const us16*)w1raw;
  int lane = threadIdx.x;
  int mx = 0;
  for (int i = lane; i < 2048; i += 64) {
    int e = (u[i] >> 7) & 0xFF;
    mx = mx > e ? mx : e;
  }
#pragma unroll
  for (int m = 32; m >= 1; m >>= 1) {
    int o = __shfl_xor(mx, m);
    mx = mx > o ? mx : o;
  }
  if (lane == 0) *flag = (mx >= 135) ? 1 : 0;  // 1 = inputs are f32
}

__global__ __launch_bounds__(256) void k_canon_feats(const void* __restrict__ src,
                                                     us16* __restrict__ dst,
                                                     const int* __restrict__ flag) {
  int i = (blockIdx.x * 256 + threadIdx.x) * 4;
  if (i >= NN * HF) return;
  if (*flag) {
    float4 v = *(const float4*)((const float*)src + i);
    ushort4 o;
    o.x = f2us(v.x); o.y = f2us(v.y); o.z = f2us(v.z); o.w = f2us(v.w);
    *(ushort4*)(dst + i) = o;
  } else {
    *(ushort4*)(dst + i) = *(const ushort4*)((const us16*)src + i);
  }
}

// parallel small-param canonicalization: grid covers all N_SMALL elems
__global__ __launch_bounds__(256) void k_canon_small(
    const void* s0, const void* s1, const void* s2, const void* s3, const void* s4,
    const void* s5, const void* s6, const void* s7, const void* s8, const void* s9,
    us16* d0, us16* d1, us16* d2, us16* d3, us16* d4,
    us16* d5, us16* d6, us16* d7, us16* d8, us16* d9,
    const int* __restrict__ flag) {
  const void* sp[10] = {s0, s1, s2, s3, s4, s5, s6, s7, s8, s9};
  us16* dp[10] = {d0, d1, d2, d3, d4, d5, d6, d7, d8, d9};
  const int cnt[10] = {16384, 16384, 128, 128, 128, 128, 128, 128, 32, 1};
  int f = *flag;
  int gid = blockIdx.x * 256 + threadIdx.x;
  int base = 0;
#pragma unroll
  for (int p = 0; p < 10; ++p) {
    int loc = gid - base;
    if (loc >= 0 && loc < cnt[p])
      dp[p][loc] = f ? f2us(((const float*)sp[p])[loc]) : ((const us16*)sp[p])[loc];
    base += cnt[p];
  }
}

// ---- CSR build
__global__ void k_count(const int* __restrict__ dst, int* __restrict__ deg) {
  int e = blockIdx.x * 256 + threadIdx.x;
  if (e < NE) atomicAdd(&deg[dst[e]], 1);
}

// hierarchical scan phase 1: per-block (1024 nodes) degree sums
__global__ __launch_bounds__(1024) void k_s1(const int* __restrict__ deg,
                                             int* __restrict__ bsum) {
  __shared__ int red[1024];
  int t = threadIdx.x;
  int i = blockIdx.x * 1024 + t;
  red[t] = (i < NN) ? deg[i] : 0;
  __syncthreads();
  for (int s = 512; s > 0; s >>= 1) {
    if (t < s) red[t] += red[t + s];
    __syncthreads();
  }
  if (t == 0) bsum[blockIdx.x] = red[0];
}

// phase 2: one wave scans the 49 block sums -> exclusive block offsets
__global__ __launch_bounds__(64) void k_s2(const int* __restrict__ bsum,
                                           int* __restrict__ boff,
                                           int* __restrict__ rowptr) {
  int lane = threadIdx.x;
  const int NB = (NN + 1023) / 1024;  // 49
  int v = (lane < NB) ? bsum[lane] : 0;
  int orig = v;
#pragma unroll
  for (int off = 1; off < 64; off <<= 1) {
    int u = __shfl_up(v, off);
    if (lane >= off) v += u;
  }
  if (lane < NB) boff[lane] = v - orig;  // exclusive
  if (lane == 0) rowptr[NN] = NE;
}

// phase 3: per-block Hillis-Steele exclusive scan + block offset -> rowptr
__global__ __launch_bounds__(1024) void k_s3(const int* __restrict__ deg,
                                             const int* __restrict__ boff,
                                             int* __restrict__ rowptr) {
  __shared__ int part[1024];
  int t = threadIdx.x;
  int i = blockIdx.x * 1024 + t;
  int d = (i < NN) ? deg[i] : 0;
  part[t] = d;
  __syncthreads();
  for (int off = 1; off < 1024; off <<= 1) {
    int v = (t >= off) ? part[t - off] : 0;
    __syncthreads();
    part[t] += v;
    __syncthreads();
  }
  if (i < NN) rowptr[i] = boff[blockIdx.x] + part[t] - d;
}

__global__ void k_scatter(const int* __restrict__ src, const int* __restrict__ dst,
                          const int* __restrict__ rowptr, int* __restrict__ fill,
                          int* __restrict__ adj) {
  int e = blockIdx.x * 256 + threadIdx.x;
  if (e < NE) {
    int d = dst[e];
    int pos = rowptr[d] + atomicAdd(&fill[d], 1);
    adj[pos] = src[e];
  }
}

// ---- MFMA GEMM: Z[N,128](bf16) = X[N,128](bf16) @ W[128,128](bf16)
// 16x16x32 bf16 MFMA. Block = 256 thr = 4 waves; each wave does 16 rows x 128 cols.
// W repacked into LDS in B-fragment order so each (ntile,kstep) is one ds_read_b128:
//   Wl element index = (((s*8 + t)*4 + q)*16 + c)*8 + j  holds  W[s*32+q*8+j][t*16+c]
// Fragment maps (m89/m120-verified): A[m=lane&15][k=q*8+j], B[k=q*8+j][n=lane&15],
// D row=q*4+reg, col=lane&15.
__global__ __launch_bounds__(256) void k_gemm(const us16* __restrict__ X,
                                              const us16* __restrict__ W,
                                              us16* __restrict__ Z) {
  __shared__ us16 Wl[HF * HF];
  int tid = threadIdx.x;
  // repack W (16384 elems, 64 per thread; coalesced 2B global reads)
  for (int e = tid; e < HF * HF; e += 256) {
    int k = e >> 7, n = e & 127;
    int d = ((((k >> 5) * 8 + (n >> 4)) * 4 + ((k >> 3) & 3)) * 16 + (n & 15)) * 8 + (k & 7);
    Wl[d] = W[e];
  }
  __syncthreads();

  int w = tid >> 6;        // wave 0..3
  int lane = tid & 63;
  int q = lane >> 4;       // quad 0..3
  int c = lane & 15;       // col-in-tile / row-in-tile
  int m0 = blockIdx.x * 64 + w * 16;

  int rA = m0 + c;                       // A-frag row for this lane
  if (rA >= NN) rA = NN - 1;             // clamp (stores are guarded)
  const us16* xrow = X + (size_t)rA * HF;

  f32x4 acc[8] = {};
#pragma unroll
  for (int s = 0; s < 4; ++s) {
    bf16x8 a = *(const bf16x8*)&xrow[s * 32 + q * 8];
#pragma unroll
    for (int t = 0; t < 8; ++t) {
      bf16x8 b = *(const bf16x8*)&Wl[((((s * 8) + t) * 4 + q) * 16 + c) * 8];
      acc[t] = __builtin_amdgcn_mfma_f32_16x16x32_bf16(a, b, acc[t], 0, 0, 0);
    }
  }

#pragma unroll
  for (int reg = 0; reg < 4; ++reg) {
    int row = m0 + q * 4 + reg;
    if (row < NN) {
      us16* zrow = Z + (size_t)row * HF;
#pragma unroll
      for (int t = 0; t < 8; ++t) zrow[t * 16 + c] = f2us(acc[t][reg]);
    }
  }
}

// el[n,h] = sum_f z[n,h,f]*al[h,f]; er likewise. 2 nodes per 256-thr block.
__global__ __launch_bounds__(256) void k_coef(const us16* __restrict__ Z,
                                              const us16* __restrict__ al,
                                              const us16* __restrict__ ar,
                                              float* __restrict__ el,
                                              float* __restrict__ er) {
  int t = threadIdx.x;
  int n = blockIdx.x * 2 + (t >> 7);
  int c = t & 127;
  float v = us2f(Z[(size_t)n * HF + c]);
  float pl = v * us2f(al[c]);
  float pr = v * us2f(ar[c]);
#pragma unroll
  for (int m = 16; m >= 1; m >>= 1) {
    pl += __shfl_xor(pl, m);
    pr += __shfl_xor(pr, m);
  }
  if ((c & 31) == 0) {
    int h = c >> 5;
    el[n * 4 + h] = pl;
    er[n * 4 + h] = pr;
  }
}

// One wave per destination node: softmax over in-edges + weighted aggregation.
template <int LAYER>
__global__ __launch_bounds__(64) void k_agg(
    const us16* __restrict__ Z, const float* __restrict__ el,
    const float* __restrict__ er, const int* __restrict__ rowptr,
    const int* __restrict__ adj, const us16* __restrict__ resid,
    const us16* __restrict__ bias, us16* __restrict__ Hout,
    const us16* __restrict__ Wp, const us16* __restrict__ bp,
    void* __restrict__ out, const int* __restrict__ flag) {
  __shared__ float scb[64 * 4];
  __shared__ int sidx[64];
  int n = blockIdx.x;
  int lane = threadIdx.x;
  int begin = rowptr[n];
  int deg = rowptr[n + 1] - begin;
  float4 er4 = *(const float4*)&er[n * 4];
  int hl = lane >> 4;   // head owning this lane's feature pair
  int c0 = lane * 2;    // feature pair c0, c0+1
  float m4[4] = {-1e30f, -1e30f, -1e30f, -1e30f};
  // pass 1: per-head max of leaky_relu(el[src]+er[n])
  for (int i = lane; i < deg; i += 64) {
    int s = adj[begin + i];
    s = ((unsigned)s < (unsigned)NN) ? s : 0;  // defensive clamp
    float4 e4 = *(const float4*)&el[s * 4];
    float s0 = e4.x + er4.x; s0 = s0 > 0.f ? s0 : 0.2f * s0;
    float s1 = e4.y + er4.y; s1 = s1 > 0.f ? s1 : 0.2f * s1;
    float s2 = e4.z + er4.z; s2 = s2 > 0.f ? s2 : 0.2f * s2;
    float s3 = e4.w + er4.w; s3 = s3 > 0.f ? s3 : 0.2f * s3;
    m4[0] = fmaxf(m4[0], s0); m4[1] = fmaxf(m4[1], s1);
    m4[2] = fmaxf(m4[2], s2); m4[3] = fmaxf(m4[3], s3);
  }
#pragma unroll
  for (int mm = 32; mm >= 1; mm >>= 1) {
#pragma unroll
    for (int h = 0; h < 4; ++h) m4[h] = fmaxf(m4[h], __shfl_xor(m4[h], mm));
  }
  float mh = m4[hl];
  // pass 2: ssum = sum exp, a = sum exp * z[src]
  float a0 = 0.f, a1 = 0.f, ssum = 0.f;
  for (int base = 0; base < deg; base += 64) {
    int cl = deg - base;
    if (cl > 64) cl = 64;
    __syncthreads();  // protect LDS reuse across chunks
    if (lane < cl) {
      int s = adj[begin + base + lane];
      s = ((unsigned)s < (unsigned)NN) ? s : 0;
      float4 e4 = *(const float4*)&el[s * 4];
      float s0 = e4.x + er4.x; s0 = s0 > 0.f ? s0 : 0.2f * s0;
      float s1 = e4.y + er4.y; s1 = s1 > 0.f ? s1 : 0.2f * s1;
      float s2 = e4.z + er4.z; s2 = s2 > 0.f ? s2 : 0.2f * s2;
      float s3 = e4.w + er4.w; s3 = s3 > 0.f ? s3 : 0.2f * s3;
      scb[lane * 4 + 0] = s0; scb[lane * 4 + 1] = s1;
      scb[lane * 4 + 2] = s2; scb[lane * 4 + 3] = s3;
      sidx[lane] = s;
    }
    __syncthreads();
    for (int i = 0; i < cl; ++i) {
      int s = sidx[i];
      float ex = __expf(scb[i * 4 + hl] - mh);
      ssum += ex;
      unsigned int zz = *(const unsigned int*)&Z[(size_t)s * HF + c0];
      float z0 = us2f((us16)(zz & 0xffffu));
      float z1 = us2f((us16)(zz >> 16));
      a0 = fmaf(ex, z0, a0);
      a1 = fmaf(ex, z1, a1);
    }
  }
  float inv = 1.f / fmaxf(ssum, 1e-9f);  // deg==0 -> a==0 -> r==0 (matches ref)
  float r0 = a0 * inv, r1 = a1 * inv;
  float bb0 = us2f(bias[c0]), bb1 = us2f(bias[c0 + 1]);
  float x0 = us2f(resid[(size_t)n * HF + c0]);
  float x1 = us2f(resid[(size_t)n * HF + c0 + 1]);
  float t0 = r0 + x0 + bb0;
  float t1 = r1 + x1 + bb1;
  if (LAYER == 1) {
    t0 = t0 > 0.f ? t0 : __expf(t0) - 1.f;  // ELU
    t1 = t1 > 0.f ? t1 : __expf(t1) - 1.f;
    unsigned int hv = ((unsigned int)f2us(t1) << 16) | (unsigned int)f2us(t0);
    *(unsigned int*)&Hout[(size_t)n * HF + c0] = hv;
  } else {
    // mean over heads: lanes {l, l^16, l^32, l^48} share the same feature pair
    t0 += __shfl_xor(t0, 16); t0 += __shfl_xor(t0, 32);
    t1 += __shfl_xor(t1, 16); t1 += __shfl_xor(t1, 32);
    t0 *= 0.25f; t1 *= 0.25f;
    // projection: each 16-lane group covers f=0..31 via its 2-feature pairs
    int f0 = c0 & 31;
    float p = t0 * us2f(Wp[f0]) + t1 * us2f(Wp[f0 + 1]);
    p += __shfl_xor(p, 8); p += __shfl_xor(p, 4);
    p += __shfl_xor(p, 2); p += __shfl_xor(p, 1);
    if (lane == 0) {
      float res = p + us2f(bp[0]);
      if (*flag) ((float*)out)[n] = res;
      else ((us16*)out)[n] = f2us(res);
    }
  }
}

extern "C" void kernel_launch(void* const* d_in, const int* in_sizes, int n_in,
                              void* d_out, int out_size, void* d_ws, size_t ws_size,
                              hipStream_t stream) {
  const int* src = (const int*)d_in[1];
  const int* dst = (const int*)d_in[2];
  char* ws = (char*)d_ws;
  int* flag   = (int*)(ws + OFF_FLAG);
  int* rowptr = (int*)(ws + OFF_ROWPTR);
  int* bsum   = (int*)(ws + OFF_BSUM);
  int* boff   = (int*)(ws + OFF_BOFF);
  int* deg    = (int*)(ws + OFF_DEG);
  int* fill   = (int*)(ws + OFF_FILL);
  int* adj    = (int*)(ws + OFF_ADJ);
  us16* fx    = (us16*)(ws + OFF_FX);
  us16* wc1   = (us16*)(ws + OFF_WC1);
  us16* wc2   = (us16*)(ws + OFF_WC2);
  us16* al1   = (us16*)(ws + OFF_PAR + 0);
  us16* ar1   = (us16*)(ws + OFF_PAR + 256);
  us16* b1    = (us16*)(ws + OFF_PAR + 512);
  us16* al2   = (us16*)(ws + OFF_PAR + 768);
  us16* ar2   = (us16*)(ws + OFF_PAR + 1024);
  us16* b2    = (us16*)(ws + OFF_PAR + 1280);
  us16* wp    = (us16*)(ws + OFF_PAR + 1536);
  us16* bp    = (us16*)(ws + OFF_PAR + 1792);
  us16* z     = (us16*)(ws + OFF_Z);
  us16* h1    = (us16*)(ws + OFF_H1);
  float* el   = (float*)(ws + OFF_EL);
  float* er   = (float*)(ws + OFF_ER);

  const int NB = (NN + 1023) / 1024;  // 49

  hipMemsetAsync(deg, 0, OFF_ADJ - OFF_DEG, stream);  // zero deg + fill

  hipLaunchKernelGGL(k_detect, dim3(1), dim3(64), 0, stream, d_in[3], flag);
  hipLaunchKernelGGL(k_canon_feats, dim3(6250), dim3(256), 0, stream, d_in[0], fx, flag);
  hipLaunchKernelGGL(k_canon_small, dim3((N_SMALL + 255) / 256), dim3(256), 0, stream,
                     d_in[3], d_in[7], d_in[4], d_in[5], d_in[6],
                     d_in[8], d_in[9], d_in[10], d_in[11], d_in[12],
                     wc1, wc2, al1, ar1, b1, al2, ar2, b2, wp, bp, flag);

  hipLaunchKernelGGL(k_count, dim3(3125), dim3(256), 0, stream, dst, deg);
  hipLaunchKernelGGL(k_s1, dim3(NB), dim3(1024), 0, stream, deg, bsum);
  hipLaunchKernelGGL(k_s2, dim3(1), dim3(64), 0, stream, bsum, boff, rowptr);
  hipLaunchKernelGGL(k_s3, dim3(NB), dim3(1024), 0, stream, deg, boff, rowptr);
  hipLaunchKernelGGL(k_scatter, dim3(3125), dim3(256), 0, stream, src, dst, rowptr, fill, adj);

  // layer 1
  hipLaunchKernelGGL(k_gemm, dim3((NN + 63) / 64), dim3(256), 0, stream, fx, wc1, z);
  hipLaunchKernelGGL(k_coef, dim3(NN / 2), dim3(256), 0, stream, z, al1, ar1, el, er);
  hipLaunchKernelGGL((k_agg<1>), dim3(NN), dim3(64), 0, stream, z, el, er, rowptr, adj,
                     fx, b1, h1, (us16*)nullptr, (us16*)nullptr, (void*)nullptr, flag);
  // layer 2 (+ fused head-mean and projection)
  hipLaunchKernelGGL(k_gemm, dim3((NN + 63) / 64), dim3(256), 0, stream, h1, wc2, z);
  hipLaunchKernelGGL(k_coef, dim3(NN / 2), dim3(256), 0, stream, z, al2, ar2, el, er);
  hipLaunchKernelGGL((k_agg<2>), dim3(NN), dim3(64), 0, stream, z, el, er, rowptr, adj,
                     h1, b2, (us16*)nullptr, wp, bp, d_out, flag);
}